// Round 6
// baseline (911.635 us; speedup 1.0000x reference)
//
#include <hip/hip_runtime.h>
#include <hip/hip_bf16.h>

#define N_NODES 100000
#define N_EDGES 640000
#define NGRAPH 16
#define STILE 4096  // scan tile: 256 threads * 16 elems

typedef __attribute__((ext_vector_type(8))) short bf16x8;  // 8 bf16 (4 VGPRs)
typedef __attribute__((ext_vector_type(4))) float f32x4;   // MFMA accumulator

// ---------------- int degree histogram (both directions) ----------------
__global__ void hist_kernel(const int* __restrict__ src, const int* __restrict__ dst,
                            int* __restrict__ dout, int* __restrict__ din, int E) {
    int i = blockIdx.x * blockDim.x + threadIdx.x;
    if (i < E) {
        atomicAdd(&dout[src[i]], 1);
        atomicAdd(&din[dst[i]], 1);
    }
}

// c_src[i] = rsqrt(max(deg_out,1))
__global__ void csrc_kernel(const int* __restrict__ dout, float* __restrict__ c_src, int n) {
    int i = blockIdx.x * blockDim.x + threadIdx.x;
    if (i < n) c_src[i] = rsqrtf(fmaxf((float)dout[i], 1.0f));
}

// ---------------- multi-block exclusive scan, phase 1: tile-local scan ----------------
__global__ __launch_bounds__(256) void scan_blocks(const int* __restrict__ deg,
                                                   int* __restrict__ local,
                                                   int* __restrict__ blk_sums, int n) {
    __shared__ int wsum[4];
    int tid = threadIdx.x;
    int lane = tid & 63, wid = tid >> 6;
    int base = blockIdx.x * STILE + tid * 16;
    int v[16];
#pragma unroll
    for (int j = 0; j < 16; j++) {
        int idx = base + j;
        v[j] = (idx < n) ? deg[idx] : 0;
    }
    int tsum = 0;
#pragma unroll
    for (int j = 0; j < 16; j++) tsum += v[j];
    int inc = tsum;
    for (int off = 1; off < 64; off <<= 1) {
        int u = __shfl_up(inc, off, 64);
        if (lane >= off) inc += u;
    }
    if (lane == 63) wsum[wid] = inc;
    __syncthreads();
    int woff = 0;
#pragma unroll
    for (int w = 0; w < 4; w++) if (w < wid) woff += wsum[w];
    int run = woff + inc - tsum;   // exclusive offset for this thread
#pragma unroll
    for (int j = 0; j < 16; j++) {
        int idx = base + j;
        if (idx < n) local[idx] = run;
        run += v[j];
    }
    if (tid == 255) blk_sums[blockIdx.x] = woff + inc;  // tile total
}

// ---------------- phase 2: scan tile totals (nb <= 64) ----------------
__global__ void scan_tops(const int* __restrict__ blk_sums, int* __restrict__ blk_off,
                          int* __restrict__ row_ptr_n, int nb) {
    int lane = threadIdx.x;
    int v = (lane < nb) ? blk_sums[lane] : 0;
    int inc = v;
    for (int off = 1; off < 64; off <<= 1) {
        int u = __shfl_up(inc, off, 64);
        if (lane >= off) inc += u;
    }
    if (lane < nb) blk_off[lane] = inc - v;
    if (lane == 63) *row_ptr_n = inc;  // total == E
}

// ---------------- phase 3: add tile offsets; produce row_ptr + fill cursor ----------------
__global__ void scan_apply(const int* __restrict__ blk_off, int* __restrict__ row_ptr,
                           int* __restrict__ cur, int n) {
    int i = blockIdx.x * blockDim.x + threadIdx.x;
    if (i < n) {
        int v = row_ptr[i] + blk_off[i >> 12];
        row_ptr[i] = v;
        cur[i] = v;
    }
}

// ---------------- CSR fill: bucket src ids by dst ----------------
__global__ void fill_kernel(const int* __restrict__ src, const int* __restrict__ dst,
                            int* __restrict__ cursor, int* __restrict__ csr_src, int E) {
    int i = blockIdx.x * blockDim.x + threadIdx.x;
    if (i < E) {
        int p = atomicAdd(&cursor[dst[i]], 1);
        csr_src[p] = src[i];
    }
}

// ---------------- W prep: Wt_h/Wt_l [M][K] bf16 from W [K][M] fp32 ----------------
__global__ void wprep_kernel(const float* __restrict__ W, unsigned short* __restrict__ Wth,
                             unsigned short* __restrict__ Wtl, int K, int M) {
    int i = blockIdx.x * blockDim.x + threadIdx.x;
    if (i >= K * M) return;
    int m = i / K, k = i - m * K;
    float w = W[(size_t)k * M + m];
    unsigned b = __float_as_uint(w);
    unsigned short h = (unsigned short)(b >> 16);
    float hf = __uint_as_float(b & 0xffff0000u);
    float lo = w - hf;
    unsigned short l = (unsigned short)(__float_as_uint(lo) >> 16);
    Wth[i] = h;
    Wtl[i] = l;
}

// ---------------- MFMA bf16x3 GEMM: out[r][c] = (sum_k X[r][k]*W[k][c]) * scale[r]
// X fp32 [n][K] (split to bf16 hi/lo while staging to LDS); Wt bf16 [M][K] (pre-split).
// 256 threads = 4 waves; block covers 64 rows x M cols; wave w owns rows [w*16, w*16+16).
template<int K, int M>
__global__ __launch_bounds__(256) void gemm_mfma(const float* __restrict__ X,
                                                 const unsigned short* __restrict__ Wth,
                                                 const unsigned short* __restrict__ Wtl,
                                                 const float* __restrict__ scale,
                                                 float* __restrict__ out, int n) {
    constexpr int KC = 64;            // k-chunk staged in LDS
    constexpr int NT = M / 16;        // 16-col tiles
    constexpr int LDSW = KC + 8;      // ushort stride: 144B rows -> 2-way conflicts only
    __shared__ unsigned short Xh[64][LDSW];
    __shared__ unsigned short Xl[64][LDSW];

    int tid = threadIdx.x;
    int lane = tid & 63, w = tid >> 6;
    int l15 = lane & 15, l4 = lane >> 4;
    int row0 = blockIdx.x * 64;

    f32x4 acc[NT];
#pragma unroll
    for (int t = 0; t < NT; t++) acc[t] = (f32x4){0.f, 0.f, 0.f, 0.f};

    for (int k0 = 0; k0 < K; k0 += KC) {
        __syncthreads();  // protect LDS from previous chunk's readers
        // ---- stage + split fp32 -> bf16 hi/lo
        constexpr int Q = KC / 4;     // float4 per row
#pragma unroll
        for (int it = 0; it < (64 * Q) / 256; it++) {
            int idx = it * 256 + tid;
            int r = idx / Q, q = idx - r * Q;
            int gr = row0 + r;
            float4 v = make_float4(0.f, 0.f, 0.f, 0.f);
            if (gr < n) v = *(const float4*)&X[(size_t)gr * K + k0 + q * 4];
            ushort4 hs, ls;
            {
                unsigned b0 = __float_as_uint(v.x), b1 = __float_as_uint(v.y);
                unsigned b2 = __float_as_uint(v.z), b3 = __float_as_uint(v.w);
                hs.x = b0 >> 16; hs.y = b1 >> 16; hs.z = b2 >> 16; hs.w = b3 >> 16;
                float l0 = v.x - __uint_as_float(b0 & 0xffff0000u);
                float l1 = v.y - __uint_as_float(b1 & 0xffff0000u);
                float l2 = v.z - __uint_as_float(b2 & 0xffff0000u);
                float l3 = v.w - __uint_as_float(b3 & 0xffff0000u);
                ls.x = __float_as_uint(l0) >> 16; ls.y = __float_as_uint(l1) >> 16;
                ls.z = __float_as_uint(l2) >> 16; ls.w = __float_as_uint(l3) >> 16;
            }
            *(ushort4*)&Xh[r][q * 4] = hs;
            *(ushort4*)&Xl[r][q * 4] = ls;
        }
        __syncthreads();
        // ---- compute: KC/32 k-steps
#pragma unroll
        for (int ks = 0; ks < KC; ks += 32) {
            int ko = ks + 8 * l4;
            bf16x8 ah = *(const bf16x8*)&Xh[w * 16 + l15][ko];
            bf16x8 al = *(const bf16x8*)&Xl[w * 16 + l15][ko];
            int kg = k0 + ko;
#pragma unroll
            for (int t = 0; t < NT; t++) {
                bf16x8 bh = *(const bf16x8*)&Wth[(size_t)(t * 16 + l15) * K + kg];
                bf16x8 bl = *(const bf16x8*)&Wtl[(size_t)(t * 16 + l15) * K + kg];
                acc[t] = __builtin_amdgcn_mfma_f32_16x16x32_bf16(ah, bh, acc[t], 0, 0, 0);
                acc[t] = __builtin_amdgcn_mfma_f32_16x16x32_bf16(ah, bl, acc[t], 0, 0, 0);
                acc[t] = __builtin_amdgcn_mfma_f32_16x16x32_bf16(al, bh, acc[t], 0, 0, 0);
            }
        }
    }
    // ---- epilogue: D row = (lane>>4)*4 + reg, col = t*16 + (lane&15)  [m89-verified]
    int rbase = row0 + w * 16 + l4 * 4;
    float s[4];
#pragma unroll
    for (int j = 0; j < 4; j++) s[j] = (rbase + j < n) ? scale[rbase + j] : 0.f;
#pragma unroll
    for (int t = 0; t < NT; t++) {
#pragma unroll
        for (int j = 0; j < 4; j++) {
            int r = rbase + j;
            if (r < n) out[(size_t)r * M + t * 16 + l15] = acc[t][j] * s[j];
        }
    }
}

// ---------------- CSR gather-sum aggregation + fused (*c_dst + b) -> relu ----------------
template<int D>
__global__ __launch_bounds__(256) void agg_relu(const float* __restrict__ x,
                                                const int* __restrict__ row_ptr,
                                                const int* __restrict__ csr_src,
                                                const float* __restrict__ bias,
                                                float* __restrict__ out, int n) {
    int lane = threadIdx.x & 63;
    int node = blockIdx.x * 4 + (threadIdx.x >> 6);
    if (node >= n) return;
    int p0 = row_ptr[node], p1 = row_ptr[node + 1];
    float cd = rsqrtf(fmaxf((float)(p1 - p0), 1.0f));
    if (D == 128) {
        float ax = 0.0f, ay = 0.0f;
        for (int p = p0; p < p1; ++p) {
            int s = csr_src[p];
            float2 v = ((const float2*)(x + ((size_t)s << 7)))[lane];
            ax += v.x; ay += v.y;
        }
        float2 b2 = ((const float2*)bias)[lane];
        float2 r;
        r.x = fmaxf(fmaf(ax, cd, b2.x), 0.0f);
        r.y = fmaxf(fmaf(ay, cd, b2.y), 0.0f);
        ((float2*)(out + ((size_t)node << 7)))[lane] = r;
    } else {
        float acc = 0.0f;
        for (int p = p0; p < p1; ++p) {
            int s = csr_src[p];
            acc += x[((size_t)s << 6) + lane];
        }
        out[((size_t)node << 6) + lane] = fmaxf(fmaf(acc, cd, bias[lane]), 0.0f);
    }
}

// ---------------- per-graph mean pooling (sum + count) ----------------
__global__ void pool_kernel(const float* __restrict__ x, const int* __restrict__ gid,
                            float* __restrict__ sums, float* __restrict__ cnts, int n) {
    __shared__ float ls[NGRAPH * 64];
    __shared__ float lc[NGRAPH];
    for (int i = threadIdx.x; i < NGRAPH * 64; i += blockDim.x) ls[i] = 0.0f;
    if (threadIdx.x < NGRAPH) lc[threadIdx.x] = 0.0f;
    __syncthreads();
    int total = n * 64;
    for (int i = blockIdx.x * blockDim.x + threadIdx.x; i < total;
         i += gridDim.x * blockDim.x) {
        int node = i >> 6, f = i & 63;
        int g = gid[node];
        atomicAdd(&ls[g * 64 + f], x[i]);
        if (f == 0) atomicAdd(&lc[g], 1.0f);
    }
    __syncthreads();
    for (int i = threadIdx.x; i < NGRAPH * 64; i += blockDim.x) atomicAdd(&sums[i], ls[i]);
    if (threadIdx.x < NGRAPH) atomicAdd(&cnts[threadIdx.x], lc[threadIdx.x]);
}

// ---------------- attention head: A = tanh(x @ aW1 + ab1) @ aW2 + ab2 ----------------
__global__ __launch_bounds__(256) void attn_kernel(const float* __restrict__ x,
                                                   const float* __restrict__ aW1,
                                                   const float* __restrict__ ab1,
                                                   const float* __restrict__ aW2,
                                                   const float* __restrict__ ab2,
                                                   float* __restrict__ A, int n) {
    __shared__ float w1[64 * 64];
    __shared__ float b1s[64];
    __shared__ float w2[64];
    for (int i = threadIdx.x; i < 64 * 64; i += 256) w1[i] = aW1[i];
    if (threadIdx.x < 64) { b1s[threadIdx.x] = ab1[threadIdx.x]; w2[threadIdx.x] = aW2[threadIdx.x]; }
    __syncthreads();
    int lane = threadIdx.x & 63;
    int wave = threadIdx.x >> 6;
    float bias2 = ab2[0];
    int node = blockIdx.x * 4 + wave;
    if (node >= n) return;
    float xv = x[(size_t)node * 64 + lane];
    float acc = b1s[lane];
#pragma unroll
    for (int k = 0; k < 64; k++) {
        float xk = __shfl(xv, k, 64);
        acc += xk * w1[k * 64 + lane];
    }
    float y = tanhf(acc);
    float p = y * w2[lane];
#pragma unroll
    for (int off = 32; off > 0; off >>= 1) p += __shfl_xor(p, off, 64);
    if (lane == 0) A[node] = p + bias2;
}

// ---------------- graph head: out = relu(hg @ cW1 + cb1) @ cW2 + cb2 ----------------
__global__ __launch_bounds__(1024) void head_kernel(const float* __restrict__ sums,
                                                    const float* __restrict__ cnts,
                                                    const float* __restrict__ cW1,
                                                    const float* __restrict__ cb1,
                                                    const float* __restrict__ cW2,
                                                    const float* __restrict__ cb2,
                                                    float* __restrict__ out) {
    __shared__ float hg[NGRAPH][64];
    __shared__ float z[NGRAPH][64];
    int tid = threadIdx.x;
    int g = tid >> 6, j = tid & 63;
    hg[g][j] = sums[tid] / fmaxf(cnts[g], 1.0f);
    __syncthreads();
    float acc = cb1[j];
#pragma unroll 4
    for (int k = 0; k < 64; k++) acc += hg[g][k] * cW1[k * 64 + j];
    z[g][j] = fmaxf(acc, 0.0f);
    __syncthreads();
    if (tid < NGRAPH * 2) {
        int gg = tid >> 1, c = tid & 1;
        float a2 = cb2[c];
#pragma unroll
        for (int jj = 0; jj < 64; jj++) a2 += z[gg][jj] * cW2[jj * 2 + c];
        out[gg * 2 + c] = a2;
    }
}

extern "C" void kernel_launch(void* const* d_in, const int* in_sizes, int n_in,
                              void* d_out, int out_size, void* d_ws, size_t ws_size,
                              hipStream_t stream) {
    const float* h   = (const float*)d_in[0];
    const int*   src = (const int*)d_in[1];
    const int*   dst = (const int*)d_in[2];
    const int*   gid = (const int*)d_in[3];
    const float* W1  = (const float*)d_in[4];
    const float* b1  = (const float*)d_in[5];
    const float* W2  = (const float*)d_in[6];
    const float* b2  = (const float*)d_in[7];
    const float* W3  = (const float*)d_in[8];
    const float* b3  = (const float*)d_in[9];
    const float* aW1 = (const float*)d_in[10];
    const float* ab1 = (const float*)d_in[11];
    const float* aW2 = (const float*)d_in[12];
    const float* ab2 = (const float*)d_in[13];
    const float* cW1 = (const float*)d_in[14];
    const float* cb1 = (const float*)d_in[15];
    const float* cW2 = (const float*)d_in[16];
    const float* cb2 = (const float*)d_in[17];

    float* out = (float*)d_out;   // 16*2 = 32 floats
    float* A   = out + 32;        // N floats

    const int N = N_NODES, E = N_EDGES;
    const int NB = (N + STILE - 1) / STILE;  // 25 scan tiles

    // ---- workspace layout (float-indexed; all large buffers 16B-aligned)
    float* ws       = (float*)d_ws;
    float* c_src    = ws;                          // N floats
    int*   row_ptr  = (int*)(ws + N);              // N+1 ints
    int*   cur      = row_ptr + (N + 1);           // N ints (din histogram -> fill cursor)
    int*   csr_src  = cur + N;                     // E ints
    int*   blk_sums = csr_src + E;                 // 64 ints
    int*   blk_off  = blk_sums + 64;               // 64 ints
    size_t off      = (size_t)N + (N + 1) + N + E + 128;
    off = (off + 15) & ~(size_t)15;
    unsigned short* wt1h = (unsigned short*)(ws + off);  // 128*256
    unsigned short* wt1l = wt1h + 128 * 256;
    unsigned short* wt2h = wt1l + 128 * 256;             // 128*128
    unsigned short* wt2l = wt2h + 128 * 128;
    unsigned short* wt3h = wt2l + 128 * 128;             // 64*128
    unsigned short* wt3l = wt3h + 64 * 128;
    off += (2 * (128 * 256 + 128 * 128 + 64 * 128)) / 2; // shorts -> floats
    off = (off + 15) & ~(size_t)15;
    float* bufA     = ws + off;                    // N*128 floats
    float* bufB     = bufA + (size_t)N * 128;      // N*128 floats
    int*   dout     = (int*)bufB;                  // N ints (aliased: consumed before bufB written)
    float* sums     = bufB + (size_t)N * 128;      // 16*64
    float* cnts     = sums + NGRAPH * 64;          // 16

    // ---- CSR build (once, reused by all 3 layers)
    hipMemsetAsync(cur, 0, N * sizeof(int), stream);
    hipMemsetAsync(dout, 0, N * sizeof(int), stream);
    hist_kernel<<<(E + 255) / 256, 256, 0, stream>>>(src, dst, dout, cur, E);
    csrc_kernel<<<(N + 255) / 256, 256, 0, stream>>>(dout, c_src, N);
    scan_blocks<<<NB, 256, 0, stream>>>(cur, row_ptr, blk_sums, N);
    scan_tops<<<1, 64, 0, stream>>>(blk_sums, blk_off, row_ptr + N, NB);
    scan_apply<<<(N + 255) / 256, 256, 0, stream>>>(blk_off, row_ptr, cur, N);
    fill_kernel<<<(E + 255) / 256, 256, 0, stream>>>(src, dst, cur, csr_src, E);

    // ---- weight transpose + bf16 hi/lo split (tiny)
    wprep_kernel<<<(256 * 128 + 255) / 256, 256, 0, stream>>>(W1, wt1h, wt1l, 256, 128);
    wprep_kernel<<<(128 * 128 + 255) / 256, 256, 0, stream>>>(W2, wt2h, wt2l, 128, 128);
    wprep_kernel<<<(128 * 64 + 255) / 256, 256, 0, stream>>>(W3, wt3h, wt3l, 128, 64);

    // ---- layer 1: bufA = (h @ W1) * c_src ; bufB = relu(agg * c_dst + b1)
    gemm_mfma<256, 128><<<(N + 63) / 64, 256, 0, stream>>>(h, wt1h, wt1l, c_src, bufA, N);
    agg_relu<128><<<(N + 3) / 4, 256, 0, stream>>>(bufA, row_ptr, csr_src, b1, bufB, N);

    // ---- layer 2
    gemm_mfma<128, 128><<<(N + 63) / 64, 256, 0, stream>>>(bufB, wt2h, wt2l, c_src, bufA, N);
    agg_relu<128><<<(N + 3) / 4, 256, 0, stream>>>(bufA, row_ptr, csr_src, b2, bufB, N);

    // ---- layer 3: t3 = bufA[0:N*64]; x3 = bufA[N*64:N*128]
    float* t3 = bufA;
    float* x3 = bufA + (size_t)N * 64;
    gemm_mfma<128, 64><<<(N + 63) / 64, 256, 0, stream>>>(bufB, wt3h, wt3l, c_src, t3, N);
    agg_relu<64><<<(N + 3) / 4, 256, 0, stream>>>(t3, row_ptr, csr_src, b3, x3, N);

    // ---- pooling
    hipMemsetAsync(sums, 0, (NGRAPH * 64 + NGRAPH) * sizeof(float), stream);
    pool_kernel<<<512, 256, 0, stream>>>(x3, gid, sums, cnts, N);

    // ---- attention scores A [N]
    attn_kernel<<<(N + 3) / 4, 256, 0, stream>>>(x3, aW1, ab1, aW2, ab2, A, N);

    // ---- graph head out [16,2]
    head_kernel<<<1, 1024, 0, stream>>>(sums, cnts, cW1, cb1, cW2, cb2, out);
}

// Round 7
// 810.334 us; speedup vs baseline: 1.1250x; 1.1250x over previous
//
#include <hip/hip_runtime.h>
#include <hip/hip_bf16.h>

#define N_NODES 100000
#define N_EDGES 640000
#define NGRAPH 16
#define STILE 4096  // scan tile: 256 threads * 16 elems

typedef __attribute__((ext_vector_type(8))) short bf16x8;  // 8 bf16 (4 VGPRs)
typedef __attribute__((ext_vector_type(4))) float f32x4;   // MFMA accumulator

// ---------------- int degree histogram (both directions) ----------------
__global__ void hist_kernel(const int* __restrict__ src, const int* __restrict__ dst,
                            int* __restrict__ dout, int* __restrict__ din, int E) {
    int i = blockIdx.x * blockDim.x + threadIdx.x;
    if (i < E) {
        atomicAdd(&dout[src[i]], 1);
        atomicAdd(&din[dst[i]], 1);
    }
}

// c_src[i] = rsqrt(max(deg_out,1))
__global__ void csrc_kernel(const int* __restrict__ dout, float* __restrict__ c_src, int n) {
    int i = blockIdx.x * blockDim.x + threadIdx.x;
    if (i < n) c_src[i] = rsqrtf(fmaxf((float)dout[i], 1.0f));
}

// ---------------- multi-block exclusive scan, phase 1: tile-local scan ----------------
__global__ __launch_bounds__(256) void scan_blocks(const int* __restrict__ deg,
                                                   int* __restrict__ local,
                                                   int* __restrict__ blk_sums, int n) {
    __shared__ int wsum[4];
    int tid = threadIdx.x;
    int lane = tid & 63, wid = tid >> 6;
    int base = blockIdx.x * STILE + tid * 16;
    int v[16];
#pragma unroll
    for (int j = 0; j < 16; j++) {
        int idx = base + j;
        v[j] = (idx < n) ? deg[idx] : 0;
    }
    int tsum = 0;
#pragma unroll
    for (int j = 0; j < 16; j++) tsum += v[j];
    int inc = tsum;
    for (int off = 1; off < 64; off <<= 1) {
        int u = __shfl_up(inc, off, 64);
        if (lane >= off) inc += u;
    }
    if (lane == 63) wsum[wid] = inc;
    __syncthreads();
    int woff = 0;
#pragma unroll
    for (int w = 0; w < 4; w++) if (w < wid) woff += wsum[w];
    int run = woff + inc - tsum;   // exclusive offset for this thread
#pragma unroll
    for (int j = 0; j < 16; j++) {
        int idx = base + j;
        if (idx < n) local[idx] = run;
        run += v[j];
    }
    if (tid == 255) blk_sums[blockIdx.x] = woff + inc;  // tile total
}

// ---------------- phase 2: scan tile totals (nb <= 64) ----------------
__global__ void scan_tops(const int* __restrict__ blk_sums, int* __restrict__ blk_off,
                          int* __restrict__ row_ptr_n, int nb) {
    int lane = threadIdx.x;
    int v = (lane < nb) ? blk_sums[lane] : 0;
    int inc = v;
    for (int off = 1; off < 64; off <<= 1) {
        int u = __shfl_up(inc, off, 64);
        if (lane >= off) inc += u;
    }
    if (lane < nb) blk_off[lane] = inc - v;
    if (lane == 63) *row_ptr_n = inc;  // total == E
}

// ---------------- phase 3: add tile offsets; produce row_ptr + fill cursor ----------------
__global__ void scan_apply(const int* __restrict__ blk_off, int* __restrict__ row_ptr,
                           int* __restrict__ cur, int n) {
    int i = blockIdx.x * blockDim.x + threadIdx.x;
    if (i < n) {
        int v = row_ptr[i] + blk_off[i >> 12];
        row_ptr[i] = v;
        cur[i] = v;
    }
}

// ---------------- CSR fill: bucket src ids by dst ----------------
__global__ void fill_kernel(const int* __restrict__ src, const int* __restrict__ dst,
                            int* __restrict__ cursor, int* __restrict__ csr_src, int E) {
    int i = blockIdx.x * blockDim.x + threadIdx.x;
    if (i < E) {
        int p = atomicAdd(&cursor[dst[i]], 1);
        csr_src[p] = src[i];
    }
}

// ---------------- W prep: fragment-ordered bf16 hi/lo from W [K][M] fp32 ----------------
// Layout: frag f = T*(K/32)+C (T=col-tile, C=k-chunk of 32); within frag, 512 shorts:
// index r = lane*8 + j  ->  col = T*16 + (lane&15), k = C*32 + (lane>>4)*8 + j.
// A bh load in the GEMM is then one contiguous 1KB segment (16B/lane, coalesced).
__global__ void wprep_kernel(const float* __restrict__ W, unsigned short* __restrict__ Wfh,
                             unsigned short* __restrict__ Wfl, int K, int M) {
    int i = blockIdx.x * blockDim.x + threadIdx.x;
    if (i >= K * M) return;
    int frag = i >> 9, r = i & 511;
    int KC32 = K >> 5;
    int T = frag / KC32, C = frag - T * KC32;
    int lane = r >> 3, j = r & 7;
    int col = T * 16 + (lane & 15);
    int k = C * 32 + (lane >> 4) * 8 + j;
    float w = W[(size_t)k * M + col];
    unsigned b = __float_as_uint(w);
    unsigned short h = (unsigned short)(b >> 16);
    float hf = __uint_as_float(b & 0xffff0000u);
    float lo = w - hf;
    unsigned short l = (unsigned short)(__float_as_uint(lo) >> 16);
    Wfh[i] = h;
    Wfl[i] = l;
}

// ---------------- MFMA bf16x3 GEMM: out[r][c] = (sum_k X[r][k]*W[k][c]) * scale[r]
// X fp32 [n][K] (split to bf16 hi/lo while staging to LDS); W pre-split, fragment-ordered.
// Block: 128 rows x M cols, 4 waves; wave w owns col-tiles [w*NTW, (w+1)*NTW).
// Each W fragment pair feeds 8 row-groups x 3 MFMAs = 24 MFMAs -> latency well hidden.
template<int K, int M>
__global__ __launch_bounds__(256) void gemm_mfma(const float* __restrict__ X,
                                                 const unsigned short* __restrict__ Wfh,
                                                 const unsigned short* __restrict__ Wfl,
                                                 const float* __restrict__ scale,
                                                 float* __restrict__ out, int n) {
    constexpr int KC = 64;            // k-chunk staged in LDS
    constexpr int NTW = M / 64;       // col-tiles per wave (M=128 -> 2, M=64 -> 1)
    constexpr int KC32 = K / 32;      // k-steps total
    constexpr int LDSW = KC + 8;      // ushort stride: 144B rows -> benign conflicts
    __shared__ unsigned short Xh[128][LDSW];
    __shared__ unsigned short Xl[128][LDSW];

    int tid = threadIdx.x;
    int lane = tid & 63, w = tid >> 6;
    int l15 = lane & 15, l4 = lane >> 4;
    int row0 = blockIdx.x * 128;

    f32x4 acc[8][NTW];
#pragma unroll
    for (int rg = 0; rg < 8; rg++)
#pragma unroll
        for (int t = 0; t < NTW; t++) acc[rg][t] = (f32x4){0.f, 0.f, 0.f, 0.f};

    for (int k0 = 0; k0 < K; k0 += KC) {
        __syncthreads();  // protect LDS from previous chunk's readers
        // ---- stage + split fp32 -> bf16 hi/lo (128 rows x KC)
        constexpr int Q = KC / 4;     // float4 per row
#pragma unroll
        for (int it = 0; it < (128 * Q) / 256; it++) {
            int idx = it * 256 + tid;
            int r = idx / Q, q = idx - r * Q;
            int gr = row0 + r;
            float4 v = make_float4(0.f, 0.f, 0.f, 0.f);
            if (gr < n) v = *(const float4*)&X[(size_t)gr * K + k0 + q * 4];
            ushort4 hs, ls;
            {
                unsigned b0 = __float_as_uint(v.x), b1 = __float_as_uint(v.y);
                unsigned b2 = __float_as_uint(v.z), b3 = __float_as_uint(v.w);
                hs.x = b0 >> 16; hs.y = b1 >> 16; hs.z = b2 >> 16; hs.w = b3 >> 16;
                float l0 = v.x - __uint_as_float(b0 & 0xffff0000u);
                float l1 = v.y - __uint_as_float(b1 & 0xffff0000u);
                float l2 = v.z - __uint_as_float(b2 & 0xffff0000u);
                float l3 = v.w - __uint_as_float(b3 & 0xffff0000u);
                ls.x = __float_as_uint(l0) >> 16; ls.y = __float_as_uint(l1) >> 16;
                ls.z = __float_as_uint(l2) >> 16; ls.w = __float_as_uint(l3) >> 16;
            }
            *(ushort4*)&Xh[r][q * 4] = hs;
            *(ushort4*)&Xl[r][q * 4] = ls;
        }
        __syncthreads();
        // ---- compute: 2 k-steps per chunk
#pragma unroll
        for (int ks = 0; ks < KC; ks += 32) {
            int ko = ks + 8 * l4;
            // A fragments: 8 row-groups, hi+lo (issued first, overlap with W loads)
            bf16x8 ah[8], al[8];
#pragma unroll
            for (int rg = 0; rg < 8; rg++) {
                ah[rg] = *(const bf16x8*)&Xh[rg * 16 + l15][ko];
                al[rg] = *(const bf16x8*)&Xl[rg * 16 + l15][ko];
            }
            int kcidx = (k0 + ks) >> 5;
            bf16x8 bh[NTW], bl[NTW];
#pragma unroll
            for (int t = 0; t < NTW; t++) {
                size_t fo = ((size_t)((w * NTW + t) * KC32 + kcidx) << 9) + (lane << 3);
                bh[t] = *(const bf16x8*)&Wfh[fo];
                bl[t] = *(const bf16x8*)&Wfl[fo];
            }
#pragma unroll
            for (int t = 0; t < NTW; t++) {
#pragma unroll
                for (int rg = 0; rg < 8; rg++) {
                    acc[rg][t] = __builtin_amdgcn_mfma_f32_16x16x32_bf16(ah[rg], bh[t], acc[rg][t], 0, 0, 0);
                    acc[rg][t] = __builtin_amdgcn_mfma_f32_16x16x32_bf16(ah[rg], bl[t], acc[rg][t], 0, 0, 0);
                    acc[rg][t] = __builtin_amdgcn_mfma_f32_16x16x32_bf16(al[rg], bh[t], acc[rg][t], 0, 0, 0);
                }
            }
        }
    }
    // ---- epilogue: D row = rg*16 + (lane>>4)*4 + reg, col = (w*NTW+t)*16 + (lane&15)
#pragma unroll
    for (int rg = 0; rg < 8; rg++) {
        int rbase = row0 + rg * 16 + l4 * 4;
        float s[4];
#pragma unroll
        for (int j = 0; j < 4; j++) s[j] = (rbase + j < n) ? scale[rbase + j] : 0.f;
#pragma unroll
        for (int t = 0; t < NTW; t++) {
            int c = (w * NTW + t) * 16 + l15;
#pragma unroll
            for (int j = 0; j < 4; j++) {
                int r = rbase + j;
                if (r < n) out[(size_t)r * M + c] = acc[rg][t][j] * s[j];
            }
        }
    }
}

// ---------------- CSR gather-sum aggregation + fused (*c_dst + b) -> relu ----------------
template<int D>
__global__ __launch_bounds__(256) void agg_relu(const float* __restrict__ x,
                                                const int* __restrict__ row_ptr,
                                                const int* __restrict__ csr_src,
                                                const float* __restrict__ bias,
                                                float* __restrict__ out, int n) {
    int lane = threadIdx.x & 63;
    int node = blockIdx.x * 4 + (threadIdx.x >> 6);
    if (node >= n) return;
    int p0 = row_ptr[node], p1 = row_ptr[node + 1];
    float cd = rsqrtf(fmaxf((float)(p1 - p0), 1.0f));
    if (D == 128) {
        float ax = 0.0f, ay = 0.0f;
        for (int p = p0; p < p1; ++p) {
            int s = csr_src[p];
            float2 v = ((const float2*)(x + ((size_t)s << 7)))[lane];
            ax += v.x; ay += v.y;
        }
        float2 b2 = ((const float2*)bias)[lane];
        float2 r;
        r.x = fmaxf(fmaf(ax, cd, b2.x), 0.0f);
        r.y = fmaxf(fmaf(ay, cd, b2.y), 0.0f);
        ((float2*)(out + ((size_t)node << 7)))[lane] = r;
    } else {
        float acc = 0.0f;
        for (int p = p0; p < p1; ++p) {
            int s = csr_src[p];
            acc += x[((size_t)s << 6) + lane];
        }
        out[((size_t)node << 6) + lane] = fmaxf(fmaf(acc, cd, bias[lane]), 0.0f);
    }
}

// ---------------- per-graph mean pooling (sum + count) ----------------
__global__ void pool_kernel(const float* __restrict__ x, const int* __restrict__ gid,
                            float* __restrict__ sums, float* __restrict__ cnts, int n) {
    __shared__ float ls[NGRAPH * 64];
    __shared__ float lc[NGRAPH];
    for (int i = threadIdx.x; i < NGRAPH * 64; i += blockDim.x) ls[i] = 0.0f;
    if (threadIdx.x < NGRAPH) lc[threadIdx.x] = 0.0f;
    __syncthreads();
    int total = n * 64;
    for (int i = blockIdx.x * blockDim.x + threadIdx.x; i < total;
         i += gridDim.x * blockDim.x) {
        int node = i >> 6, f = i & 63;
        int g = gid[node];
        atomicAdd(&ls[g * 64 + f], x[i]);
        if (f == 0) atomicAdd(&lc[g], 1.0f);
    }
    __syncthreads();
    for (int i = threadIdx.x; i < NGRAPH * 64; i += blockDim.x) atomicAdd(&sums[i], ls[i]);
    if (threadIdx.x < NGRAPH) atomicAdd(&cnts[threadIdx.x], lc[threadIdx.x]);
}

// ---------------- attention head: A = tanh(x @ aW1 + ab1) @ aW2 + ab2 ----------------
__global__ __launch_bounds__(256) void attn_kernel(const float* __restrict__ x,
                                                   const float* __restrict__ aW1,
                                                   const float* __restrict__ ab1,
                                                   const float* __restrict__ aW2,
                                                   const float* __restrict__ ab2,
                                                   float* __restrict__ A, int n) {
    __shared__ float w1[64 * 64];
    __shared__ float b1s[64];
    __shared__ float w2[64];
    for (int i = threadIdx.x; i < 64 * 64; i += 256) w1[i] = aW1[i];
    if (threadIdx.x < 64) { b1s[threadIdx.x] = ab1[threadIdx.x]; w2[threadIdx.x] = aW2[threadIdx.x]; }
    __syncthreads();
    int lane = threadIdx.x & 63;
    int wave = threadIdx.x >> 6;
    float bias2 = ab2[0];
    int node = blockIdx.x * 4 + wave;
    if (node >= n) return;
    float xv = x[(size_t)node * 64 + lane];
    float acc = b1s[lane];
#pragma unroll
    for (int k = 0; k < 64; k++) {
        float xk = __shfl(xv, k, 64);
        acc += xk * w1[k * 64 + lane];
    }
    float y = tanhf(acc);
    float p = y * w2[lane];
#pragma unroll
    for (int off = 32; off > 0; off >>= 1) p += __shfl_xor(p, off, 64);
    if (lane == 0) A[node] = p + bias2;
}

// ---------------- graph head: out = relu(hg @ cW1 + cb1) @ cW2 + cb2 ----------------
__global__ __launch_bounds__(1024) void head_kernel(const float* __restrict__ sums,
                                                    const float* __restrict__ cnts,
                                                    const float* __restrict__ cW1,
                                                    const float* __restrict__ cb1,
                                                    const float* __restrict__ cW2,
                                                    const float* __restrict__ cb2,
                                                    float* __restrict__ out) {
    __shared__ float hg[NGRAPH][64];
    __shared__ float z[NGRAPH][64];
    int tid = threadIdx.x;
    int g = tid >> 6, j = tid & 63;
    hg[g][j] = sums[tid] / fmaxf(cnts[g], 1.0f);
    __syncthreads();
    float acc = cb1[j];
#pragma unroll 4
    for (int k = 0; k < 64; k++) acc += hg[g][k] * cW1[k * 64 + j];
    z[g][j] = fmaxf(acc, 0.0f);
    __syncthreads();
    if (tid < NGRAPH * 2) {
        int gg = tid >> 1, c = tid & 1;
        float a2 = cb2[c];
#pragma unroll
        for (int jj = 0; jj < 64; jj++) a2 += z[gg][jj] * cW2[jj * 2 + c];
        out[gg * 2 + c] = a2;
    }
}

extern "C" void kernel_launch(void* const* d_in, const int* in_sizes, int n_in,
                              void* d_out, int out_size, void* d_ws, size_t ws_size,
                              hipStream_t stream) {
    const float* h   = (const float*)d_in[0];
    const int*   src = (const int*)d_in[1];
    const int*   dst = (const int*)d_in[2];
    const int*   gid = (const int*)d_in[3];
    const float* W1  = (const float*)d_in[4];
    const float* b1  = (const float*)d_in[5];
    const float* W2  = (const float*)d_in[6];
    const float* b2  = (const float*)d_in[7];
    const float* W3  = (const float*)d_in[8];
    const float* b3  = (const float*)d_in[9];
    const float* aW1 = (const float*)d_in[10];
    const float* ab1 = (const float*)d_in[11];
    const float* aW2 = (const float*)d_in[12];
    const float* ab2 = (const float*)d_in[13];
    const float* cW1 = (const float*)d_in[14];
    const float* cb1 = (const float*)d_in[15];
    const float* cW2 = (const float*)d_in[16];
    const float* cb2 = (const float*)d_in[17];

    float* out = (float*)d_out;   // 16*2 = 32 floats
    float* A   = out + 32;        // N floats

    const int N = N_NODES, E = N_EDGES;
    const int NB = (N + STILE - 1) / STILE;  // 25 scan tiles

    // ---- workspace layout (float-indexed; all large buffers 16B-aligned)
    float* ws       = (float*)d_ws;
    float* c_src    = ws;                          // N floats
    int*   row_ptr  = (int*)(ws + N);              // N+1 ints
    int*   cur      = row_ptr + (N + 1);           // N ints (din histogram -> fill cursor)
    int*   csr_src  = cur + N;                     // E ints
    int*   blk_sums = csr_src + E;                 // 64 ints
    int*   blk_off  = blk_sums + 64;               // 64 ints
    size_t off      = (size_t)N + (N + 1) + N + E + 128;
    off = (off + 15) & ~(size_t)15;
    unsigned short* wt1h = (unsigned short*)(ws + off);  // 128*256
    unsigned short* wt1l = wt1h + 128 * 256;
    unsigned short* wt2h = wt1l + 128 * 256;             // 128*128
    unsigned short* wt2l = wt2h + 128 * 128;
    unsigned short* wt3h = wt2l + 128 * 128;             // 64*128
    unsigned short* wt3l = wt3h + 64 * 128;
    off += (2 * (128 * 256 + 128 * 128 + 64 * 128)) / 2; // shorts -> floats
    off = (off + 15) & ~(size_t)15;
    float* bufA     = ws + off;                    // N*128 floats
    float* bufB     = bufA + (size_t)N * 128;      // N*128 floats
    int*   dout     = (int*)bufB;                  // N ints (aliased: consumed before bufB written)
    float* sums     = bufB + (size_t)N * 128;      // 16*64
    float* cnts     = sums + NGRAPH * 64;          // 16

    // ---- CSR build (once, reused by all 3 layers)
    hipMemsetAsync(cur, 0, N * sizeof(int), stream);
    hipMemsetAsync(dout, 0, N * sizeof(int), stream);
    hist_kernel<<<(E + 255) / 256, 256, 0, stream>>>(src, dst, dout, cur, E);
    csrc_kernel<<<(N + 255) / 256, 256, 0, stream>>>(dout, c_src, N);
    scan_blocks<<<NB, 256, 0, stream>>>(cur, row_ptr, blk_sums, N);
    scan_tops<<<1, 64, 0, stream>>>(blk_sums, blk_off, row_ptr + N, NB);
    scan_apply<<<(N + 255) / 256, 256, 0, stream>>>(blk_off, row_ptr, cur, N);
    fill_kernel<<<(E + 255) / 256, 256, 0, stream>>>(src, dst, cur, csr_src, E);

    // ---- weight fragment prep (tiny)
    wprep_kernel<<<(256 * 128 + 255) / 256, 256, 0, stream>>>(W1, wt1h, wt1l, 256, 128);
    wprep_kernel<<<(128 * 128 + 255) / 256, 256, 0, stream>>>(W2, wt2h, wt2l, 128, 128);
    wprep_kernel<<<(128 * 64 + 255) / 256, 256, 0, stream>>>(W3, wt3h, wt3l, 128, 64);

    // ---- layer 1: bufA = (h @ W1) * c_src ; bufB = relu(agg * c_dst + b1)
    gemm_mfma<256, 128><<<(N + 127) / 128, 256, 0, stream>>>(h, wt1h, wt1l, c_src, bufA, N);
    agg_relu<128><<<(N + 3) / 4, 256, 0, stream>>>(bufA, row_ptr, csr_src, b1, bufB, N);

    // ---- layer 2
    gemm_mfma<128, 128><<<(N + 127) / 128, 256, 0, stream>>>(bufB, wt2h, wt2l, c_src, bufA, N);
    agg_relu<128><<<(N + 3) / 4, 256, 0, stream>>>(bufA, row_ptr, csr_src, b2, bufB, N);

    // ---- layer 3: t3 = bufA[0:N*64]; x3 = bufA[N*64:N*128]
    float* t3 = bufA;
    float* x3 = bufA + (size_t)N * 64;
    gemm_mfma<128, 64><<<(N + 127) / 128, 256, 0, stream>>>(bufB, wt3h, wt3l, c_src, t3, N);
    agg_relu<64><<<(N + 3) / 4, 256, 0, stream>>>(t3, row_ptr, csr_src, b3, x3, N);

    // ---- pooling
    hipMemsetAsync(sums, 0, (NGRAPH * 64 + NGRAPH) * sizeof(float), stream);
    pool_kernel<<<512, 256, 0, stream>>>(x3, gid, sums, cnts, N);

    // ---- attention scores A [N]
    attn_kernel<<<(N + 3) / 4, 256, 0, stream>>>(x3, aW1, ab1, aW2, ab2, A, N);

    // ---- graph head out [16,2]
    head_kernel<<<1, 1024, 0, stream>>>(sums, cnts, cW1, cb1, cW2, cb2, out);
}

// Round 8
// 735.467 us; speedup vs baseline: 1.2395x; 1.1018x over previous
//
#include <hip/hip_runtime.h>
#include <hip/hip_bf16.h>

#define N_NODES 100000
#define N_EDGES 640000
#define NGRAPH 16
#define STILE 4096  // scan tile: 256 threads * 16 elems

typedef __attribute__((ext_vector_type(8))) short bf16x8;  // 8 bf16 (4 VGPRs)
typedef __attribute__((ext_vector_type(4))) float f32x4;   // MFMA accumulator

// ---------------- int degree histogram (both directions) ----------------
__global__ void hist_kernel(const int* __restrict__ src, const int* __restrict__ dst,
                            int* __restrict__ dout, int* __restrict__ din, int E) {
    int i = blockIdx.x * blockDim.x + threadIdx.x;
    if (i < E) {
        atomicAdd(&dout[src[i]], 1);
        atomicAdd(&din[dst[i]], 1);
    }
}

// c_src[i] = rsqrt(max(deg_out,1))
__global__ void csrc_kernel(const int* __restrict__ dout, float* __restrict__ c_src, int n) {
    int i = blockIdx.x * blockDim.x + threadIdx.x;
    if (i < n) c_src[i] = rsqrtf(fmaxf((float)dout[i], 1.0f));
}

// ---------------- multi-block exclusive scan, phase 1: tile-local scan ----------------
__global__ __launch_bounds__(256) void scan_blocks(const int* __restrict__ deg,
                                                   int* __restrict__ local,
                                                   int* __restrict__ blk_sums, int n) {
    __shared__ int wsum[4];
    int tid = threadIdx.x;
    int lane = tid & 63, wid = tid >> 6;
    int base = blockIdx.x * STILE + tid * 16;
    int v[16];
#pragma unroll
    for (int j = 0; j < 16; j++) {
        int idx = base + j;
        v[j] = (idx < n) ? deg[idx] : 0;
    }
    int tsum = 0;
#pragma unroll
    for (int j = 0; j < 16; j++) tsum += v[j];
    int inc = tsum;
    for (int off = 1; off < 64; off <<= 1) {
        int u = __shfl_up(inc, off, 64);
        if (lane >= off) inc += u;
    }
    if (lane == 63) wsum[wid] = inc;
    __syncthreads();
    int woff = 0;
#pragma unroll
    for (int w = 0; w < 4; w++) if (w < wid) woff += wsum[w];
    int run = woff + inc - tsum;   // exclusive offset for this thread
#pragma unroll
    for (int j = 0; j < 16; j++) {
        int idx = base + j;
        if (idx < n) local[idx] = run;
        run += v[j];
    }
    if (tid == 255) blk_sums[blockIdx.x] = woff + inc;  // tile total
}

// ---------------- phase 2: scan tile totals (nb <= 64) ----------------
__global__ void scan_tops(const int* __restrict__ blk_sums, int* __restrict__ blk_off,
                          int* __restrict__ row_ptr_n, int nb) {
    int lane = threadIdx.x;
    int v = (lane < nb) ? blk_sums[lane] : 0;
    int inc = v;
    for (int off = 1; off < 64; off <<= 1) {
        int u = __shfl_up(inc, off, 64);
        if (lane >= off) inc += u;
    }
    if (lane < nb) blk_off[lane] = inc - v;
    if (lane == 63) *row_ptr_n = inc;  // total == E
}

// ---------------- phase 3: add tile offsets; produce row_ptr + fill cursor ----------------
__global__ void scan_apply(const int* __restrict__ blk_off, int* __restrict__ row_ptr,
                           int* __restrict__ cur, int n) {
    int i = blockIdx.x * blockDim.x + threadIdx.x;
    if (i < n) {
        int v = row_ptr[i] + blk_off[i >> 12];
        row_ptr[i] = v;
        cur[i] = v;
    }
}

// ---------------- CSR fill: bucket src ids by dst ----------------
__global__ void fill_kernel(const int* __restrict__ src, const int* __restrict__ dst,
                            int* __restrict__ cursor, int* __restrict__ csr_src, int E) {
    int i = blockIdx.x * blockDim.x + threadIdx.x;
    if (i < E) {
        int p = atomicAdd(&cursor[dst[i]], 1);
        csr_src[p] = src[i];
    }
}

// ---------------- W prep: fragment-ordered bf16 hi/lo from W [K][M] fp32 ----------------
// Layout: frag f = T*(K/32)+C (T=col-tile, C=k-chunk of 32); within frag, 512 shorts:
// index r = lane*8 + j  ->  col = T*16 + (lane&15), k = C*32 + (lane>>4)*8 + j.
__global__ void wprep_kernel(const float* __restrict__ W, unsigned short* __restrict__ Wfh,
                             unsigned short* __restrict__ Wfl, int K, int M) {
    int i = blockIdx.x * blockDim.x + threadIdx.x;
    if (i >= K * M) return;
    int frag = i >> 9, r = i & 511;
    int KC32 = K >> 5;
    int T = frag / KC32, C = frag - T * KC32;
    int lane = r >> 3, j = r & 7;
    int col = T * 16 + (lane & 15);
    int k = C * 32 + (lane >> 4) * 8 + j;
    float w = W[(size_t)k * M + col];
    unsigned b = __float_as_uint(w);
    unsigned short h = (unsigned short)(b >> 16);
    float hf = __uint_as_float(b & 0xffff0000u);
    float lo = w - hf;
    unsigned short l = (unsigned short)(__float_as_uint(lo) >> 16);
    Wfh[i] = h;
    Wfl[i] = l;
}

// ---------------- MFMA bf16x3 GEMM ----------------
// EPI=0: out[r][c] = acc * scale[r]   (GCN pre-normalize)
// EPI=1: out[r][c] = tanh(acc + scale[c])  (attention hidden layer; scale = bias)
template<int K, int M, int EPI>
__global__ __launch_bounds__(256) void gemm_mfma(const float* __restrict__ X,
                                                 const unsigned short* __restrict__ Wfh,
                                                 const unsigned short* __restrict__ Wfl,
                                                 const float* __restrict__ scale,
                                                 float* __restrict__ out, int n) {
    constexpr int KC = 64;            // k-chunk staged in LDS
    constexpr int NTW = M / 64;       // col-tiles per wave
    constexpr int KC32 = K / 32;      // k-steps total
    constexpr int LDSW = KC + 8;
    __shared__ unsigned short Xh[128][LDSW];
    __shared__ unsigned short Xl[128][LDSW];

    int tid = threadIdx.x;
    int lane = tid & 63, w = tid >> 6;
    int l15 = lane & 15, l4 = lane >> 4;
    int row0 = blockIdx.x * 128;

    f32x4 acc[8][NTW];
#pragma unroll
    for (int rg = 0; rg < 8; rg++)
#pragma unroll
        for (int t = 0; t < NTW; t++) acc[rg][t] = (f32x4){0.f, 0.f, 0.f, 0.f};

    for (int k0 = 0; k0 < K; k0 += KC) {
        __syncthreads();
        constexpr int Q = KC / 4;
#pragma unroll
        for (int it = 0; it < (128 * Q) / 256; it++) {
            int idx = it * 256 + tid;
            int r = idx / Q, q = idx - r * Q;
            int gr = row0 + r;
            float4 v = make_float4(0.f, 0.f, 0.f, 0.f);
            if (gr < n) v = *(const float4*)&X[(size_t)gr * K + k0 + q * 4];
            ushort4 hs, ls;
            {
                unsigned b0 = __float_as_uint(v.x), b1 = __float_as_uint(v.y);
                unsigned b2 = __float_as_uint(v.z), b3 = __float_as_uint(v.w);
                hs.x = b0 >> 16; hs.y = b1 >> 16; hs.z = b2 >> 16; hs.w = b3 >> 16;
                float l0 = v.x - __uint_as_float(b0 & 0xffff0000u);
                float l1 = v.y - __uint_as_float(b1 & 0xffff0000u);
                float l2 = v.z - __uint_as_float(b2 & 0xffff0000u);
                float l3 = v.w - __uint_as_float(b3 & 0xffff0000u);
                ls.x = __float_as_uint(l0) >> 16; ls.y = __float_as_uint(l1) >> 16;
                ls.z = __float_as_uint(l2) >> 16; ls.w = __float_as_uint(l3) >> 16;
            }
            *(ushort4*)&Xh[r][q * 4] = hs;
            *(ushort4*)&Xl[r][q * 4] = ls;
        }
        __syncthreads();
#pragma unroll
        for (int ks = 0; ks < KC; ks += 32) {
            int ko = ks + 8 * l4;
            bf16x8 ah[8], al[8];
#pragma unroll
            for (int rg = 0; rg < 8; rg++) {
                ah[rg] = *(const bf16x8*)&Xh[rg * 16 + l15][ko];
                al[rg] = *(const bf16x8*)&Xl[rg * 16 + l15][ko];
            }
            int kcidx = (k0 + ks) >> 5;
            bf16x8 bh[NTW], bl[NTW];
#pragma unroll
            for (int t = 0; t < NTW; t++) {
                size_t fo = ((size_t)((w * NTW + t) * KC32 + kcidx) << 9) + (lane << 3);
                bh[t] = *(const bf16x8*)&Wfh[fo];
                bl[t] = *(const bf16x8*)&Wfl[fo];
            }
#pragma unroll
            for (int t = 0; t < NTW; t++) {
#pragma unroll
                for (int rg = 0; rg < 8; rg++) {
                    acc[rg][t] = __builtin_amdgcn_mfma_f32_16x16x32_bf16(ah[rg], bh[t], acc[rg][t], 0, 0, 0);
                    acc[rg][t] = __builtin_amdgcn_mfma_f32_16x16x32_bf16(ah[rg], bl[t], acc[rg][t], 0, 0, 0);
                    acc[rg][t] = __builtin_amdgcn_mfma_f32_16x16x32_bf16(al[rg], bh[t], acc[rg][t], 0, 0, 0);
                }
            }
        }
    }
    // ---- epilogue: D row = rg*16 + (lane>>4)*4 + reg, col = (w*NTW+t)*16 + (lane&15)
#pragma unroll
    for (int rg = 0; rg < 8; rg++) {
        int rbase = row0 + rg * 16 + l4 * 4;
        if (EPI == 0) {
            float s[4];
#pragma unroll
            for (int j = 0; j < 4; j++) s[j] = (rbase + j < n) ? scale[rbase + j] : 0.f;
#pragma unroll
            for (int t = 0; t < NTW; t++) {
                int c = (w * NTW + t) * 16 + l15;
#pragma unroll
                for (int j = 0; j < 4; j++) {
                    int r = rbase + j;
                    if (r < n) out[(size_t)r * M + c] = acc[rg][t][j] * s[j];
                }
            }
        } else {
#pragma unroll
            for (int t = 0; t < NTW; t++) {
                int c = (w * NTW + t) * 16 + l15;
                float b = scale[c];
#pragma unroll
                for (int j = 0; j < 4; j++) {
                    int r = rbase + j;
                    if (r < n) out[(size_t)r * M + c] = tanhf(acc[rg][t][j] + b);
                }
            }
        }
    }
}

// ---------------- CSR gather-sum aggregation + fused (*c_dst + b) -> relu ----------------
template<int D>
__global__ __launch_bounds__(256) void agg_relu(const float* __restrict__ x,
                                                const int* __restrict__ row_ptr,
                                                const int* __restrict__ csr_src,
                                                const float* __restrict__ bias,
                                                float* __restrict__ out, int n) {
    int lane = threadIdx.x & 63;
    int node = blockIdx.x * 4 + (threadIdx.x >> 6);
    if (node >= n) return;
    int p0 = row_ptr[node], p1 = row_ptr[node + 1];
    float cd = rsqrtf(fmaxf((float)(p1 - p0), 1.0f));
    if (D == 128) {
        float ax = 0.0f, ay = 0.0f;
        for (int p = p0; p < p1; ++p) {
            int s = csr_src[p];
            float2 v = ((const float2*)(x + ((size_t)s << 7)))[lane];
            ax += v.x; ay += v.y;
        }
        float2 b2 = ((const float2*)bias)[lane];
        float2 r;
        r.x = fmaxf(fmaf(ax, cd, b2.x), 0.0f);
        r.y = fmaxf(fmaf(ay, cd, b2.y), 0.0f);
        ((float2*)(out + ((size_t)node << 7)))[lane] = r;
    } else {
        float acc = 0.0f;
        for (int p = p0; p < p1; ++p) {
            int s = csr_src[p];
            acc += x[((size_t)s << 6) + lane];
        }
        out[((size_t)node << 6) + lane] = fmaxf(fmaf(acc, cd, bias[lane]), 0.0f);
    }
}

// ---------------- per-graph mean pooling (sum + count) ----------------
__global__ void pool_kernel(const float* __restrict__ x, const int* __restrict__ gid,
                            float* __restrict__ sums, float* __restrict__ cnts, int n) {
    __shared__ float ls[NGRAPH * 64];
    __shared__ float lc[NGRAPH];
    for (int i = threadIdx.x; i < NGRAPH * 64; i += blockDim.x) ls[i] = 0.0f;
    if (threadIdx.x < NGRAPH) lc[threadIdx.x] = 0.0f;
    __syncthreads();
    int total = n * 64;
    for (int i = blockIdx.x * blockDim.x + threadIdx.x; i < total;
         i += gridDim.x * blockDim.x) {
        int node = i >> 6, f = i & 63;
        int g = gid[node];
        atomicAdd(&ls[g * 64 + f], x[i]);
        if (f == 0) atomicAdd(&lc[g], 1.0f);
    }
    __syncthreads();
    for (int i = threadIdx.x; i < NGRAPH * 64; i += blockDim.x) atomicAdd(&sums[i], ls[i]);
    if (threadIdx.x < NGRAPH) atomicAdd(&cnts[threadIdx.x], lc[threadIdx.x]);
}

// ---------------- attention dot: A[node] = dot(y[node], aW2) + ab2 ----------------
__global__ __launch_bounds__(256) void attn_dot(const float* __restrict__ y,
                                                const float* __restrict__ aW2,
                                                const float* __restrict__ ab2,
                                                float* __restrict__ A, int n) {
    int lane = threadIdx.x & 63;
    int node = blockIdx.x * 4 + (threadIdx.x >> 6);
    if (node >= n) return;
    float p = y[((size_t)node << 6) + lane] * aW2[lane];
#pragma unroll
    for (int off = 32; off > 0; off >>= 1) p += __shfl_xor(p, off, 64);
    if (lane == 0) A[node] = p + ab2[0];
}

// ---------------- graph head: out = relu(hg @ cW1 + cb1) @ cW2 + cb2 ----------------
__global__ __launch_bounds__(1024) void head_kernel(const float* __restrict__ sums,
                                                    const float* __restrict__ cnts,
                                                    const float* __restrict__ cW1,
                                                    const float* __restrict__ cb1,
                                                    const float* __restrict__ cW2,
                                                    const float* __restrict__ cb2,
                                                    float* __restrict__ out) {
    __shared__ float hg[NGRAPH][64];
    __shared__ float z[NGRAPH][64];
    int tid = threadIdx.x;
    int g = tid >> 6, j = tid & 63;
    hg[g][j] = sums[tid] / fmaxf(cnts[g], 1.0f);
    __syncthreads();
    float acc = cb1[j];
#pragma unroll 4
    for (int k = 0; k < 64; k++) acc += hg[g][k] * cW1[k * 64 + j];
    z[g][j] = fmaxf(acc, 0.0f);
    __syncthreads();
    if (tid < NGRAPH * 2) {
        int gg = tid >> 1, c = tid & 1;
        float a2 = cb2[c];
#pragma unroll
        for (int jj = 0; jj < 64; jj++) a2 += z[gg][jj] * cW2[jj * 2 + c];
        out[gg * 2 + c] = a2;
    }
}

extern "C" void kernel_launch(void* const* d_in, const int* in_sizes, int n_in,
                              void* d_out, int out_size, void* d_ws, size_t ws_size,
                              hipStream_t stream) {
    const float* h   = (const float*)d_in[0];
    const int*   src = (const int*)d_in[1];
    const int*   dst = (const int*)d_in[2];
    const int*   gid = (const int*)d_in[3];
    const float* W1  = (const float*)d_in[4];
    const float* b1  = (const float*)d_in[5];
    const float* W2  = (const float*)d_in[6];
    const float* b2  = (const float*)d_in[7];
    const float* W3  = (const float*)d_in[8];
    const float* b3  = (const float*)d_in[9];
    const float* aW1 = (const float*)d_in[10];
    const float* ab1 = (const float*)d_in[11];
    const float* aW2 = (const float*)d_in[12];
    const float* ab2 = (const float*)d_in[13];
    const float* cW1 = (const float*)d_in[14];
    const float* cb1 = (const float*)d_in[15];
    const float* cW2 = (const float*)d_in[16];
    const float* cb2 = (const float*)d_in[17];

    float* out = (float*)d_out;   // 16*2 = 32 floats
    float* A   = out + 32;        // N floats

    const int N = N_NODES, E = N_EDGES;
    const int NB = (N + STILE - 1) / STILE;  // 25 scan tiles

    // ---- workspace layout (float-indexed; all large buffers 16B-aligned)
    float* ws       = (float*)d_ws;
    float* c_src    = ws;                          // N floats
    int*   row_ptr  = (int*)(ws + N);              // N+1 ints
    int*   cur      = row_ptr + (N + 1);           // N ints
    int*   csr_src  = cur + N;                     // E ints
    int*   blk_sums = csr_src + E;                 // 64 ints
    int*   blk_off  = blk_sums + 64;               // 64 ints
    size_t off      = (size_t)N + (N + 1) + N + E + 128;
    off = (off + 15) & ~(size_t)15;
    unsigned short* wt1h = (unsigned short*)(ws + off);  // 128*256
    unsigned short* wt1l = wt1h + 128 * 256;
    unsigned short* wt2h = wt1l + 128 * 256;             // 128*128
    unsigned short* wt2l = wt2h + 128 * 128;
    unsigned short* wt3h = wt2l + 128 * 128;             // 64*128
    unsigned short* wt3l = wt3h + 64 * 128;
    unsigned short* wahh = wt3l + 64 * 128;              // 64*64 (attn aW1)
    unsigned short* wahl = wahh + 64 * 64;
    off += (2 * (128 * 256 + 128 * 128 + 64 * 128 + 64 * 64)) / 2; // shorts -> floats
    off = (off + 15) & ~(size_t)15;
    float* bufA     = ws + off;                    // N*128 floats
    float* bufB     = bufA + (size_t)N * 128;      // N*128 floats
    int*   dout     = (int*)bufB;                  // N ints (aliased: consumed before bufB written)
    float* sums     = bufB + (size_t)N * 128;      // 16*64
    float* cnts     = sums + NGRAPH * 64;          // 16

    // ---- CSR build (once, reused by all 3 layers)
    hipMemsetAsync(cur, 0, N * sizeof(int), stream);
    hipMemsetAsync(dout, 0, N * sizeof(int), stream);
    hist_kernel<<<(E + 255) / 256, 256, 0, stream>>>(src, dst, dout, cur, E);
    csrc_kernel<<<(N + 255) / 256, 256, 0, stream>>>(dout, c_src, N);
    scan_blocks<<<NB, 256, 0, stream>>>(cur, row_ptr, blk_sums, N);
    scan_tops<<<1, 64, 0, stream>>>(blk_sums, blk_off, row_ptr + N, NB);
    scan_apply<<<(N + 255) / 256, 256, 0, stream>>>(blk_off, row_ptr, cur, N);
    fill_kernel<<<(E + 255) / 256, 256, 0, stream>>>(src, dst, cur, csr_src, E);

    // ---- weight fragment prep (tiny)
    wprep_kernel<<<(256 * 128 + 255) / 256, 256, 0, stream>>>(W1, wt1h, wt1l, 256, 128);
    wprep_kernel<<<(128 * 128 + 255) / 256, 256, 0, stream>>>(W2, wt2h, wt2l, 128, 128);
    wprep_kernel<<<(128 * 64 + 255) / 256, 256, 0, stream>>>(W3, wt3h, wt3l, 128, 64);
    wprep_kernel<<<(64 * 64 + 255) / 256, 256, 0, stream>>>(aW1, wahh, wahl, 64, 64);

    // ---- layer 1: bufA = (h @ W1) * c_src ; bufB = relu(agg * c_dst + b1)
    gemm_mfma<256, 128, 0><<<(N + 127) / 128, 256, 0, stream>>>(h, wt1h, wt1l, c_src, bufA, N);
    agg_relu<128><<<(N + 3) / 4, 256, 0, stream>>>(bufA, row_ptr, csr_src, b1, bufB, N);

    // ---- layer 2
    gemm_mfma<128, 128, 0><<<(N + 127) / 128, 256, 0, stream>>>(bufB, wt2h, wt2l, c_src, bufA, N);
    agg_relu<128><<<(N + 3) / 4, 256, 0, stream>>>(bufA, row_ptr, csr_src, b2, bufB, N);

    // ---- layer 3: t3 = bufA[0:N*64]; x3 = bufA[N*64:N*128]
    float* t3 = bufA;
    float* x3 = bufA + (size_t)N * 64;
    gemm_mfma<128, 64, 0><<<(N + 127) / 128, 256, 0, stream>>>(bufB, wt3h, wt3l, c_src, t3, N);
    agg_relu<64><<<(N + 3) / 4, 256, 0, stream>>>(t3, row_ptr, csr_src, b3, x3, N);

    // ---- pooling
    hipMemsetAsync(sums, 0, (NGRAPH * 64 + NGRAPH) * sizeof(float), stream);
    pool_kernel<<<512, 256, 0, stream>>>(x3, gid, sums, cnts, N);

    // ---- attention: y = tanh(x3 @ aW1 + ab1) -> bufB ; A = y @ aW2 + ab2
    float* y = bufB;
    gemm_mfma<64, 64, 1><<<(N + 127) / 128, 256, 0, stream>>>(x3, wahh, wahl, ab1, y, N);
    attn_dot<<<(N + 3) / 4, 256, 0, stream>>>(y, aW2, ab2, A, N);

    // ---- graph head out [16,2]
    head_kernel<<<1, 1024, 0, stream>>>(sums, cnts, cW1, cb1, cW2, cb2, out);
}